// Round 1
// baseline (141.450 us; speedup 1.0000x reference)
//
#include <hip/hip_runtime.h>

#define TAU 3.0f
#define FIX 0.2f

// Layout: lane = k (K=32), group of 32 lanes = one (b,n) pedestrian.
// Wave (64 lanes) covers 2 pedestrians. idx/mask reads fully coalesced.
__global__ __launch_bounds__(256) void rvo_kernel(
    const float* __restrict__ p_cur,     // (B,N,2)
    const float* __restrict__ v_cur,     // (B,N,2)
    const float* __restrict__ v_desire,  // (B,N,2)
    const int*   __restrict__ near_idx,  // (B,N,K)
    const float* __restrict__ mask_arr,  // (B,N,K)
    const int*   __restrict__ cth,       // scalar
    float*       __restrict__ out,       // (B,N,2)
    int BN, int N)
{
    const int tid  = blockIdx.x * blockDim.x + threadIdx.x;
    const int k    = tid & 31;
    const int pair = tid >> 5;           // b*N + n
    if (pair >= BN) return;
    const int b = pair / N;

    const float thr = (float)cth[0];

    // per-pedestrian scalars (broadcast load across the 32-lane group)
    const float px  = p_cur[pair * 2 + 0];
    const float py  = p_cur[pair * 2 + 1];
    const float vdx = v_desire[pair * 2 + 0];
    const float vdy = v_desire[pair * 2 + 1];

    // coalesced per-lane reads
    const size_t nk = (size_t)pair * 32 + k;
    const int   idx = near_idx[nk];
    const float m   = mask_arr[nk];

    const float* pb = p_cur + (size_t)b * N * 2;
    const float* vb = v_cur + (size_t)b * N * 2;

    // gathered neighbor (L1/L2 resident: 8KB per batch)
    const float npx = pb[idx * 2 + 0] * m;
    const float npy = pb[idx * 2 + 1] * m;
    const float nvx = vb[idx * 2 + 0] * m;
    const float nvy = vb[idx * 2 + 1] * m;

    const float rpx = px - npx, rpy = py - npy;
    const float rvx = vdx - nvx, rvy = vdy - nvy;

    const float dpv = rpx * rvx + rpy * rvy;
    const float dvv = rvx * rvx + rvy * rvy + 1e-6f;   // ref adds 1e-6 here...
    float t = dpv / (dvv + 1e-6f);                     // ...and again here
    if (t != t) t = TAU;
    t = fminf(fmaxf(t, 0.0f), TAU);

    const float cx = rpx + t * rvx;
    const float cy = rpy + t * rvy;
    float md = sqrtf(cx * cx + cy * cy);
    if (md != md) md = 1e6f;

    const bool coll = (md < thr) && (m != 0.0f);
    const float nrm = sqrtf(rpx * rpx + rpy * rpy);
    const float den = nrm + 1e-6f;
    float nx = coll ? (-rpy) / den : 0.0f;
    float ny = coll ? ( rpx) / den : 0.0f;

    // width-32 shuffle reduction over k
    #pragma unroll
    for (int d = 16; d > 0; d >>= 1) {
        nx += __shfl_down(nx, d, 32);
        ny += __shfl_down(ny, d, 32);
    }

    if (k == 0) {
        float ox = vdx + nx * FIX;
        float oy = vdy + ny * FIX;
        if (ox != ox) ox = vdx;  // nan_to_num on correction (won't trigger w/ finite in)
        if (oy != oy) oy = vdy;
        out[pair * 2 + 0] = ox;
        out[pair * 2 + 1] = oy;
    }
}

extern "C" void kernel_launch(void* const* d_in, const int* in_sizes, int n_in,
                              void* d_out, int out_size, void* d_ws, size_t ws_size,
                              hipStream_t stream) {
    const float* p_cur    = (const float*)d_in[0];
    const float* v_cur    = (const float*)d_in[1];
    const float* v_desire = (const float*)d_in[2];
    const int*   near_idx = (const int*)d_in[3];
    const float* mask_arr = (const float*)d_in[4];
    const int*   cth      = (const int*)d_in[5];
    float*       out      = (float*)d_out;

    const int N  = 1024;                 // per reference setup
    const int BN = in_sizes[0] / 2;      // B*N
    const int total = BN * 32;           // one thread per (b,n,k), K=32

    dim3 block(256);
    dim3 grid((total + 255) / 256);
    rvo_kernel<<<grid, block, 0, stream>>>(p_cur, v_cur, v_desire, near_idx,
                                           mask_arr, cth, out, BN, N);
}

// Round 2
// 106.440 us; speedup vs baseline: 1.3289x; 1.3289x over previous
//
#include <hip/hip_runtime.h>

#define TAU 3.0f
#define FIX 0.2f
#define NPED 1024              // N per batch (reference setup)
#define PEDS_PER_BLOCK 256
#define BLOCK 512

// Layout: 8 lanes per pedestrian (sub = tid&7), each lane handles 4 neighbors.
// LDS holds the batch's packed (px,py,vx,vy) table; gathers are ds_read_b128.
__global__ __launch_bounds__(BLOCK) void rvo_kernel(
    const float* __restrict__ p_cur,     // (B,N,2)
    const float* __restrict__ v_cur,     // (B,N,2)
    const float* __restrict__ v_desire,  // (B,N,2)
    const int*   __restrict__ near_idx,  // (B,N,32)
    const float* __restrict__ mask_arr,  // (B,N,32)
    const int*   __restrict__ cth,       // scalar
    float*       __restrict__ out,       // (B,N,2)
    int N)
{
    __shared__ float4 table[NPED];

    const int tid    = threadIdx.x;
    const int bpb    = N / PEDS_PER_BLOCK;          // blocks per batch
    const int batch  = blockIdx.x / bpb;
    const int pbase  = (blockIdx.x % bpb) * PEDS_PER_BLOCK;

    // ---- stage packed (p,v) table for this batch: coalesced float2 reads ----
    const float2* pb2 = (const float2*)(p_cur) + (size_t)batch * N;
    const float2* vb2 = (const float2*)(v_cur) + (size_t)batch * N;
    for (int n = tid; n < N; n += BLOCK) {
        float2 pp = pb2[n];
        float2 vv = vb2[n];
        table[n] = make_float4(pp.x, pp.y, vv.x, vv.y);
    }
    __syncthreads();

    const float thr2 = (float)cth[0] * (float)cth[0];

    const int sub  = tid & 7;        // which 4-neighbor chunk (k = sub*4..sub*4+3)
    const int pgrp = tid >> 3;       // 0..63: pedestrian within pass

    #pragma unroll
    for (int pass = 0; pass < PEDS_PER_BLOCK / (BLOCK / 8); ++pass) {
        const int ped  = pbase + pass * (BLOCK / 8) + pgrp;
        const size_t pair = (size_t)batch * N + ped;

        // broadcast per-ped scalars (8 lanes same address)
        const float4 self = table[ped];                 // px,py (vx,vy unused)
        const float2 vd   = ((const float2*)v_desire)[pair];
        const float px = self.x, py = self.y;
        const float vdx = vd.x, vdy = vd.y;

        // coalesced vector loads: 32 idx/mask per ped = 8 int4/float4
        const int4   i4 = ((const int4*)near_idx)[pair * 8 + sub];
        const float4 m4 = ((const float4*)mask_arr)[pair * 8 + sub];
        const int   idxs[4] = {i4.x, i4.y, i4.z, i4.w};
        const float ms[4]   = {m4.x, m4.y, m4.z, m4.w};

        float nx = 0.0f, ny = 0.0f;
        #pragma unroll
        for (int j = 0; j < 4; ++j) {
            const float4 nb = table[idxs[j]];           // LDS gather, 16B
            const float m = ms[j];
            const float rpx = px  - nb.x * m;
            const float rpy = py  - nb.y * m;
            const float rvx = vdx - nb.z * m;
            const float rvy = vdy - nb.w * m;

            const float dpv = rpx * rvx + rpy * rvy;
            const float dvv = rvx * rvx + rvy * rvy + 1e-6f;
            float t = dpv * __builtin_amdgcn_rcpf(dvv + 1e-6f);
            t = fminf(fmaxf(t, 0.0f), TAU);             // inputs finite -> no NaN

            const float cx = rpx + t * rvx;
            const float cy = rpy + t * rvy;
            const float md2 = cx * cx + cy * cy;        // compare squared dist

            const bool coll = (md2 < thr2) && (m != 0.0f);

            const float s   = rpx * rpx + rpy * rpy;
            // exact den: idx==self & mask==1 gives s==0, needs 0/1e-6 == 0
            const float inv = __builtin_amdgcn_rcpf(__builtin_amdgcn_sqrtf(s) + 1e-6f);
            const float sel = coll ? inv : 0.0f;
            nx = fmaf(-rpy, sel, nx);
            ny = fmaf( rpx, sel, ny);
        }

        // width-8 reduction over sub
        #pragma unroll
        for (int d = 4; d > 0; d >>= 1) {
            nx += __shfl_down(nx, d, 8);
            ny += __shfl_down(ny, d, 8);
        }

        if (sub == 0) {
            ((float2*)out)[pair] = make_float2(fmaf(nx, FIX, vdx),
                                               fmaf(ny, FIX, vdy));
        }
    }
}

extern "C" void kernel_launch(void* const* d_in, const int* in_sizes, int n_in,
                              void* d_out, int out_size, void* d_ws, size_t ws_size,
                              hipStream_t stream) {
    const float* p_cur    = (const float*)d_in[0];
    const float* v_cur    = (const float*)d_in[1];
    const float* v_desire = (const float*)d_in[2];
    const int*   near_idx = (const int*)d_in[3];
    const float* mask_arr = (const float*)d_in[4];
    const int*   cth      = (const int*)d_in[5];
    float*       out      = (float*)d_out;

    const int N  = NPED;
    const int BN = in_sizes[0] / 2;          // B*N pedestrians
    dim3 block(BLOCK);
    dim3 grid(BN / PEDS_PER_BLOCK);          // 1024 blocks for B=256
    rvo_kernel<<<grid, block, 0, stream>>>(p_cur, v_cur, v_desire, near_idx,
                                           mask_arr, cth, out, N);
}